// Round 1
// 139.797 us; speedup vs baseline: 1.1039x; 1.1039x over previous
//
#include <hip/hip_runtime.h>
#include <math.h>

namespace {

constexpr int Bb = 8, Ss = 4, Nq = 1024, PSq = 256; // PS*PS
constexpr int Himg = 256, Wimg = 256;
constexpr float EPS_B = 1e-4f;
constexpr int MIN_CORR = 6;
constexpr int NBS = Bb * Ss;            // 32
constexpr int BLOCKS_PER_BS = 16;       // fused-kernel chunks per (b,s)
constexpr int PATCHES_PER_BLOCK = Nq / BLOCKS_PER_BS; // 64
constexpr int PART_STRIDE = 48;         // doubles per partial record (41 used)

__device__ constexpr int tidx4(int i, int j) {
  // flat index into upper triangle of symmetric 4x4, order (0,0),(0,1)...(3,3)
  const int a = i < j ? i : j;
  const int b = i < j ? j : i;
  return a * 4 - a * (a - 1) / 2 + (b - a);
}

__device__ inline double det3(const double A[3][3]) {
  return A[0][0] * (A[1][1] * A[2][2] - A[1][2] * A[2][1])
       - A[0][1] * (A[1][0] * A[2][2] - A[1][2] * A[2][0])
       + A[0][2] * (A[1][0] * A[2][1] - A[1][1] * A[2][0]);
}

// ---------------------------------------------------------------------------
// Fused kernel: phase 1 streams dense_b/dense_weight (the 67 MB floor) and
// computes per-patch weights into LDS; phase 2 (wave 0, one patch per lane)
// computes the 40 f64 DLT moment terms + valid count, shuffle-reduces, and
// writes one 41-double partial per block.
// Grid: 512 blocks (16 per bs) -> 2048 waves = 8/CU, enough to saturate HBM.
// ---------------------------------------------------------------------------
__global__ __launch_bounds__(256, 2) void fused_moments_kernel(
    const float* __restrict__ db, const float* __restrict__ dw,
    const int*   __restrict__ patch_cls,
    const float* __restrict__ K,
    const float* __restrict__ poses,
    const float* __restrict__ depth,
    double* __restrict__ part)
{
  const int blk   = blockIdx.x;                  // 0..511
  const int bs    = blk / BLOCKS_PER_BS;
  const int chunk = blk - bs * BLOCKS_PER_BS;
  const int tid   = threadIdx.x;
  const int lane  = tid & 63, wv = tid >> 6;

  __shared__ float lds_w[PATCHES_PER_BLOCK];

  // ---- phase 1: w_patch = mean( dw / (max(db,eps)+eps) ), 1 wave-shot/patch
  const size_t patch_base = (size_t)bs * Nq + (size_t)chunk * PATCHES_PER_BLOCK;
  #pragma unroll
  for (int i = 0; i < PATCHES_PER_BLOCK / 4; i++) {   // 16 patches per wave
    const int pl = wv * (PATCHES_PER_BLOCK / 4) + i;
    const size_t off = (patch_base + pl) * PSq + (size_t)lane * 4;
    const float4 bv  = *reinterpret_cast<const float4*>(db + off);
    const float4 wvv = *reinterpret_cast<const float4*>(dw + off);
    float s = wvv.x / (fmaxf(bv.x, EPS_B) + EPS_B)
            + wvv.y / (fmaxf(bv.y, EPS_B) + EPS_B)
            + wvv.z / (fmaxf(bv.z, EPS_B) + EPS_B)
            + wvv.w / (fmaxf(bv.w, EPS_B) + EPS_B);
    #pragma unroll
    for (int o = 32; o > 0; o >>= 1) s += __shfl_down(s, o);
    if (lane == 0) lds_w[pl] = s * (1.0f / 256.0f);
  }
  __syncthreads();

  // ---- phase 2: wave 0 only, one patch per lane (64 patches per block)
  if (wv == 0) {
    const float* Kt = K + ((size_t)bs / Ss * (Ss + 1) + 1 + (bs % Ss)) * 9;
    const double fx = Kt[0], cx = Kt[2], fy = Kt[4], cy = Kt[5];
    const float* Tm = poses + ((size_t)(bs / Ss) * (Ss + 1) + 1 + (bs % Ss)) * 16;
    double Rt[3][3], tinv[3];
    #pragma unroll
    for (int i = 0; i < 3; i++)
      #pragma unroll
      for (int j = 0; j < 3; j++) Rt[i][j] = (double)Tm[j * 4 + i]; // R^T
    {
      const double t0 = Tm[3], t1 = Tm[7], t2 = Tm[11];
      #pragma unroll
      for (int i = 0; i < 3; i++)
        tinv[i] = -(Rt[i][0] * t0 + Rt[i][1] * t1 + Rt[i][2] * t2);
    }

    const int n = chunk * PATCHES_PER_BLOCK + lane;  // patch index within bs
    const int pc   = patch_cls[(size_t)bs * Nq + n];
    const float wp = lds_w[lane];
    const bool mask = (pc >= 0) && (pc < Nq) && (wp > 0.0f);
    const double w = mask ? (double)wp : 0.0;
    const int buddy = min(max(pc, 0), Nq - 1);
    // centers are exactly (k%32)*8+4, (k/32)*8+4 -> round/clip is identity
    const int xj = (buddy & 31) * 8 + 4;
    const int yj = (buddy >> 5) * 8 + 4;
    const float* dimg = depth + (size_t)bs * Himg * Wimg;
    const double dep = (double)dimg[yj * Wimg + xj];
    const double xn = ((double)xj - cx) / fx;
    const double yn = ((double)yj - cy) / fy;
    const double Xc = xn * dep, Yc = yn * dep, Zc = dep;
    const double h0 = Rt[0][0] * Xc + Rt[0][1] * Yc + Rt[0][2] * Zc + tinv[0];
    const double h1 = Rt[1][0] * Xc + Rt[1][1] * Yc + Rt[1][2] * Zc + tinv[1];
    const double h2 = Rt[2][0] * Xc + Rt[2][1] * Yc + Rt[2][2] * Zc + tinv[2];
    const double u = (double)((n & 31) * 8 + 4);
    const double v = (double)((n >> 5) * 8 + 4);
    const double h[4] = {h0, h1, h2, 1.0};
    const double wu = w * u, wvw = w * v, wuv = w * (u * u + v * v);

    double m[41];
    int k = 0;
    #pragma unroll
    for (int i = 0; i < 4; i++)
      #pragma unroll
      for (int j = i; j < 4; j++) {
        const double hh = h[i] * h[j];
        m[k]      = w   * hh;
        m[10 + k] = wu  * hh;
        m[20 + k] = wvw * hh;
        m[30 + k] = wuv * hh;
        k++;
      }
    m[40] = mask ? 1.0 : 0.0;

    // 64-lane shuffle reduction of all 41 values; lane 0 holds the sums.
    #pragma unroll
    for (int a = 0; a < 41; a++) {
      double x = m[a];
      #pragma unroll
      for (int o = 32; o > 0; o >>= 1) x += __shfl_down(x, o);
      m[a] = x;
    }
    if (lane == 0) {
      double* p = part + (size_t)blk * PART_STRIDE;
      #pragma unroll
      for (int a = 0; a < 41; a++) p[a] = m[a];
    }
  }
}

// ---------------------------------------------------------------------------
// Solve kernel: one wave; lane = bs. Sums the 16 block partials, then
// register Cholesky (SPD), K^-1, sign fix, fixed-sweep Jacobi SVD, pose
// error, cross-lane reduce. Unchanged numerics vs the verified version.
// ---------------------------------------------------------------------------
__global__ __launch_bounds__(64, 1) void solve_finalize_kernel(
    const double* __restrict__ part,
    const float* __restrict__ K,
    const float* __restrict__ gt_pose,
    float* __restrict__ out)
{
  const int lane = threadIdx.x;
  double per = 0.0;
  float ctr = 0.0f;

  if (lane < NBS) {
    const int bs = lane;
    const int b  = bs / Ss;

    double S[41];
    #pragma unroll
    for (int a = 0; a < 41; a++) S[a] = 0.0;
    #pragma unroll
    for (int c = 0; c < BLOCKS_PER_BS; c++) {
      const double* p = part + ((size_t)bs * BLOCKS_PER_BS + c) * PART_STRIDE;
      #pragma unroll
      for (int a = 0; a < 41; a++) S[a] += p[a];
    }
    const int mtot = (int)(S[40] + 0.5);
    const double* M0f  = S;
    const double* Muf  = S + 10;
    const double* Mvf  = S + 20;
    const double* Muvf = S + 30;

    // G element (11x11 symmetric) from the moment blocks.
    auto Gel = [&](int i, int j) -> double {
      if (i > j) { const int t = i; i = j; j = t; }
      double g;
      if (j < 4) {
        g = M0f[tidx4(i, j)];
      } else if (j < 8) {
        g = (i < 4) ? 0.0 : M0f[tidx4(i - 4, j - 4)];
      } else {
        if (i < 4)      g = -Muf[tidx4(i, j - 8)];
        else if (i < 8) g = -Mvf[tidx4(i - 4, j - 8)];
        else            g = Muvf[tidx4(i - 8, j - 8)];
      }
      if (i == j) g += 1e-6;
      return g;
    };

    // Lower triangle of G in registers, then in-place Cholesky.
    double A[66], rhs[11];
    #pragma unroll
    for (int i = 0; i < 11; i++) {
      #pragma unroll
      for (int j = 0; j <= i; j++) A[i * (i + 1) / 2 + j] = Gel(i, j);
      rhs[i] = (i < 4) ? Muf[tidx4(i, 3)]
             : (i < 8) ? Mvf[tidx4(i - 4, 3)]
                       : -Muvf[tidx4(i - 8, 3)];
    }
    #pragma unroll
    for (int j = 0; j < 11; j++) {
      double d = A[j * (j + 1) / 2 + j];
      #pragma unroll
      for (int k = 0; k < j; k++) {
        const double l = A[j * (j + 1) / 2 + k];
        d -= l * l;
      }
      d = sqrt(d);
      A[j * (j + 1) / 2 + j] = d;
      const double inv = 1.0 / d;
      #pragma unroll
      for (int i = j + 1; i < 11; i++) {
        double sv = A[i * (i + 1) / 2 + j];
        #pragma unroll
        for (int k = 0; k < j; k++)
          sv -= A[i * (i + 1) / 2 + k] * A[j * (j + 1) / 2 + k];
        A[i * (i + 1) / 2 + j] = sv * inv;
      }
    }
    // forward solve L y = rhs
    #pragma unroll
    for (int i = 0; i < 11; i++) {
      double sv = rhs[i];
      #pragma unroll
      for (int k = 0; k < i; k++) sv -= A[i * (i + 1) / 2 + k] * rhs[k];
      rhs[i] = sv / A[i * (i + 1) / 2 + i];
    }
    // back solve L^T p = y
    #pragma unroll
    for (int ii = 10; ii >= 0; ii--) {
      double sv = rhs[ii];
      #pragma unroll
      for (int k = ii + 1; k < 11; k++) sv -= A[k * (k + 1) / 2 + ii] * rhs[k];
      rhs[ii] = sv / A[ii * (ii + 1) / 2 + ii];
    }

    const double P3[3][4] = {{rhs[0], rhs[1], rhs[2],  rhs[3]},
                             {rhs[4], rhs[5], rhs[6],  rhs[7]},
                             {rhs[8], rhs[9], rhs[10], 1.0}};
    // K_q^{-1} via adjugate
    const float* Kq = K + (size_t)b * (Ss + 1) * 9;
    const double k00 = Kq[0], k01 = Kq[1], k02 = Kq[2];
    const double k10 = Kq[3], k11 = Kq[4], k12 = Kq[5];
    const double k20 = Kq[6], k21 = Kq[7], k22 = Kq[8];
    const double dK = k00 * (k11 * k22 - k12 * k21) - k01 * (k10 * k22 - k12 * k20)
                    + k02 * (k10 * k21 - k11 * k20);
    const double iK[3][3] = {
      {(k11 * k22 - k12 * k21) / dK, (k02 * k21 - k01 * k22) / dK, (k01 * k12 - k02 * k11) / dK},
      {(k12 * k20 - k10 * k22) / dK, (k00 * k22 - k02 * k20) / dK, (k02 * k10 - k00 * k12) / dK},
      {(k10 * k21 - k11 * k20) / dK, (k01 * k20 - k00 * k21) / dK, (k00 * k11 - k01 * k10) / dK}};
    double M[3][4];
    #pragma unroll
    for (int i = 0; i < 3; i++)
      #pragma unroll
      for (int j = 0; j < 4; j++)
        M[i][j] = iK[i][0] * P3[0][j] + iK[i][1] * P3[1][j] + iK[i][2] * P3[2][j];
    double M3[3][3];
    #pragma unroll
    for (int i = 0; i < 3; i++)
      #pragma unroll
      for (int j = 0; j < 3; j++) M3[i][j] = M[i][j];
    const double dm = det3(M3);
    const double sgn = (dm > 0.0) ? 1.0 : ((dm < 0.0) ? -1.0 : 0.0);
    #pragma unroll
    for (int i = 0; i < 3; i++) {
      #pragma unroll
      for (int j = 0; j < 4; j++) M[i][j] *= sgn;
      #pragma unroll
      for (int j = 0; j < 3; j++) M3[i][j] *= sgn;
    }

    // One-sided Jacobi SVD, fixed 10 sweeps (uniform control flow).
    double Am[3][3], Vm[3][3] = {{1, 0, 0}, {0, 1, 0}, {0, 0, 1}};
    #pragma unroll
    for (int i = 0; i < 3; i++)
      #pragma unroll
      for (int j = 0; j < 3; j++) Am[i][j] = M3[i][j];
    for (int sweep = 0; sweep < 10; sweep++) {
      #pragma unroll
      for (int pr = 0; pr < 3; pr++) {
        const int pp = (pr == 2) ? 1 : 0;
        const int qq = (pr == 0) ? 1 : 2;
        double al = 0.0, be = 0.0, ga = 0.0;
        #pragma unroll
        for (int i = 0; i < 3; i++) {
          al += Am[i][pp] * Am[i][pp];
          be += Am[i][qq] * Am[i][qq];
          ga += Am[i][pp] * Am[i][qq];
        }
        if (ga != 0.0) {
          const double tau = (be - al) / (2.0 * ga);
          const double tt = -((tau >= 0.0) ? 1.0 : -1.0) /
                            (fabs(tau) + sqrt(1.0 + tau * tau));
          const double c = 1.0 / sqrt(1.0 + tt * tt), sn = tt * c;
          #pragma unroll
          for (int i = 0; i < 3; i++) {
            const double ap = Am[i][pp], aq = Am[i][qq];
            Am[i][pp] = c * ap + sn * aq; Am[i][qq] = -sn * ap + c * aq;
            const double vp = Vm[i][pp], vq = Vm[i][qq];
            Vm[i][pp] = c * vp + sn * vq; Vm[i][qq] = -sn * vp + c * vq;
          }
        }
      }
    }
    double sig[3];
    #pragma unroll
    for (int j = 0; j < 3; j++)
      sig[j] = sqrt(Am[0][j] * Am[0][j] + Am[1][j] * Am[1][j] + Am[2][j] * Am[2][j]);
    // sort singular values descending (permute columns)
    #pragma unroll
    for (int a = 0; a < 3; a++)
      #pragma unroll
      for (int jj = 0; jj < 2; jj++)
        if (sig[jj] < sig[jj + 1]) {
          double tq = sig[jj]; sig[jj] = sig[jj + 1]; sig[jj + 1] = tq;
          #pragma unroll
          for (int i = 0; i < 3; i++) {
            tq = Am[i][jj]; Am[i][jj] = Am[i][jj + 1]; Am[i][jj + 1] = tq;
            tq = Vm[i][jj]; Vm[i][jj] = Vm[i][jj + 1]; Vm[i][jj + 1] = tq;
          }
        }
    double U[3][3];
    #pragma unroll
    for (int j = 0; j < 3; j++) {
      const double invs = 1.0 / fmax(sig[j], 1e-300);
      #pragma unroll
      for (int i = 0; i < 3; i++) U[i][j] = Am[i][j] * invs;
    }
    const double dd = (det3(U) * det3(Vm) >= 0.0) ? 1.0 : -1.0;
    double R[3][3];
    #pragma unroll
    for (int i = 0; i < 3; i++)
      #pragma unroll
      for (int j = 0; j < 3; j++)
        R[i][j] = U[i][0] * Vm[j][0] + U[i][1] * Vm[j][1] + dd * U[i][2] * Vm[j][2];
    const double meanD = (sig[0] + sig[1] + sig[2]) * (1.0 / 3.0);
    const double tp0 = M[0][3] / meanD, tp1 = M[1][3] / meanD, tp2 = M[2][3] / meanD;

    const float* Tg = gt_pose + (size_t)bs * 16;
    double tr = 0.0;
    #pragma unroll
    for (int i = 0; i < 3; i++)
      #pragma unroll
      for (int j = 0; j < 3; j++) tr += R[i][j] * (double)Tg[i * 4 + j];
    double ca = (tr - 1.0) * 0.5;
    ca = fmin(fmax(ca, -1.0 + 1e-7), 1.0 - 1e-7);
    const double rot = acos(ca);
    const double d0 = tp0 - (double)Tg[3];
    const double d1 = tp1 - (double)Tg[7];
    const double d2 = tp2 - (double)Tg[11];
    ctr = (mtot >= MIN_CORR) ? 1.0f : 0.0f;
    per = (rot + sqrt(d0 * d0 + d1 * d1 + d2 * d2)) * (double)ctr;
  }

  // Cross-lane reduction over all 64 lanes (lanes >= 32 contribute 0).
  #pragma unroll
  for (int off = 32; off > 0; off >>= 1) {
    per += __shfl_down(per, off);
    ctr += __shfl_down(ctr, off);
  }
  if (lane == 0) out[0] = (float)(per / (double)fmaxf(ctr, 1.0f));
}

} // namespace

extern "C" void kernel_launch(void* const* d_in, const int* in_sizes, int n_in,
                              void* d_out, int out_size, void* d_ws, size_t ws_size,
                              hipStream_t stream) {
  // setup_inputs order:
  // 0 dense_flow (unused), 1 dense_b, 2 dense_weight, 3 patch_cls,
  // 4 K, 5 poses, 6 gt_pose, 7 template_depth
  const float* dense_b      = (const float*)d_in[1];
  const float* dense_weight = (const float*)d_in[2];
  const int*   patch_cls    = (const int*)d_in[3];
  const float* K            = (const float*)d_in[4];
  const float* poses        = (const float*)d_in[5];
  const float* gt           = (const float*)d_in[6];
  const float* depth        = (const float*)d_in[7];

  double* part = (double*)d_ws; // NBS*BLOCKS_PER_BS * PART_STRIDE doubles = 192 KiB

  fused_moments_kernel<<<dim3(NBS * BLOCKS_PER_BS), dim3(256), 0, stream>>>(
      dense_b, dense_weight, patch_cls, K, poses, depth, part);
  solve_finalize_kernel<<<dim3(1), dim3(64), 0, stream>>>(part, K, gt, (float*)d_out);
}